// Round 5
// baseline (215.690 us; speedup 1.0000x reference)
//
#include <hip/hip_runtime.h>

// GaussianVideo3D2D: N gaussians -> (T=4, H=128, W=128, C=3) fp32 volume.
// Single kernel, grid = 1024 blocks (4 t x 64 two-row slabs x 4 gaussian
// quarters) x 512 thr (8 waves). 3 blocks/CU (LDS 25.6 KB, VGPR<=84) =
// 24 waves/CU for latency hiding.
//
// Phase 1 (prep): thread n computes its quarter's gaussian record for this
//   block's t into LDS: earg(x,y) = A x^2 + B y^2 + C xy + Dx x + Dy y + E
//   (log2 domain, -0.5*log2e and log2(alpha) folded), dens = exp2(earg).
//   record = {A,B,C,Dx | Dy,E,s,fr | fg,fb,DxD,CD}, s = exp2(2A*DX^2).
// Phase 2 (splat): lane = oct(16 x-octs of 8 px) x row(2) x half(2 gaussians
//   per wave-iter, 2-address LDS broadcast = free). e0=exp2(u), r0=exp2(.),
//   then e*=r, r*=s recurrence over the 8-px run.
// Phase 3 (reduce): shfl_xor(32), dump to pad-25 LDS slots (conflict-free),
//   768 partials per block summed over 8 waves, written to d_ws.
// Phase 4 (combine): per-tile arrival counter in d_ws; atomicAdd old&3==3
//   elects the last of the tile's 4 quarter-blocks (works from ANY counter
//   init value incl. 0xAA poison; exactly one of 4 consecutive olds is
//   3 mod 4; self-maintaining across graph replays). Elected block fences,
//   volatile-reads all 4 partials in fixed g order (bitwise deterministic),
//   clips, writes the 768 contiguous output floats.

#define GV_H 128
#define GV_W 128
#define GV_T 4
#define GV_NMAX 1024
#define GV_DX 0.015625f                       // 2/128
#define K_HALF_LOG2E (-0.72134752044448170f)  // -0.5 * log2(e)

__global__ __launch_bounds__(512, 6) void gv_fused_kernel(
    const float* __restrict__ xyz, const float* __restrict__ chol,
    const float* __restrict__ feats, const float* __restrict__ opac,
    float* __restrict__ out, float* __restrict__ pws,
    unsigned int* __restrict__ cnt, int N)
{
    // union buffer: phase1/2 records (<=3072 floats), phase3 dump (6400)
    __shared__ __align__(16) float sbuf[6400];   // 25.6 KB
    __shared__ int s_last;

    int b    = blockIdx.x;        // [t(2b) | slab(6b) | gq(2b)]
    int gq   = b & 3;
    int slab = (b >> 2) & 63;
    int t    = b >> 8;
    int tile = t * 64 + slab;
    int tid  = threadIdx.x;

    int q  = (N + 3) >> 2;        // gaussians per quarter
    int gb = gq * q;
    int Ng = N - gb;
    if (Ng > q) Ng = q;
    if (Ng < 0) Ng = 0;

    // ---------------- Phase 1: prep (1 record / thread) --------------------
    if (tid < Ng) {
        int n = gb + tid;
        float mx = tanhf(xyz[n * 3 + 0]);
        float my = tanhf(xyz[n * 3 + 1]);
        float mt = tanhf(xyz[n * 3 + 2]);

        const float sc = 2.0f * 16.0f / (float)GV_W;  // SCALE = 0.25
        float L00 = sc * (chol[n * 6 + 0] + 0.5f);
        float L10 = sc * (chol[n * 6 + 1]);
        float L20 = sc * (chol[n * 6 + 2]);
        float L11 = sc * (chol[n * 6 + 3] + 0.5f);
        float L21 = sc * (chol[n * 6 + 4]);
        float L22 = sc * (chol[n * 6 + 5] + 0.5f);

        float il0 = 1.0f / L00, il1 = 1.0f / L11, il2 = 1.0f / L22;
        float m10 = -L10 * il0 * il1;
        float m21 = -L21 * il1 * il2;
        float m20 = (L10 * L21 - L11 * L20) * (il0 * il1 * il2);
        float a   = il0 * il0 + m10 * m10 + m20 * m20;
        float sab = m10 * il1 + m20 * m21;
        float sat = m20 * il2;
        float bb  = il1 * il1 + m21 * m21;
        float sbt = m21 * il2;
        float cc  = il2 * il2;
        float ab2 = 2.0f * sab, at2 = 2.0f * sat, bt2 = 2.0f * sbt;

        float o = opac[n];
        float alpha = 1.0f / (1.0f + expf(-o));
        float bias = log2f(alpha);

        float tv = ((float)t + 0.5f) * (2.0f / (float)GV_T) - 1.0f;
        float dt = tv - mt;

        const float k = K_HALF_LOG2E;
        float A  = k * a;
        float B  = k * bb;
        float C  = k * ab2;
        float Dx = k * (at2 * dt - 2.0f * a * mx - ab2 * my);
        float Dy = k * (bt2 * dt - 2.0f * bb * my - ab2 * mx);
        float E  = k * (a * mx * mx + bb * my * my + cc * dt * dt
                        + ab2 * mx * my - at2 * mx * dt - bt2 * my * dt) + bias;

        float fr = feats[n * 3 + 0];
        float fg = feats[n * 3 + 1];
        float fb = feats[n * 3 + 2];

        float sx  = exp2f(2.0f * A * GV_DX * GV_DX);
        float DxD = Dx * GV_DX;
        float CD  = C * GV_DX;

        float4* rec = (float4*)&sbuf[tid * 12];
        rec[0] = make_float4(A, B, C, Dx);
        rec[1] = make_float4(Dy, E, sx, fr);
        rec[2] = make_float4(fg, fb, DxD, CD);
    }
    __syncthreads();

    // ---------------- Phase 2: splat ---------------------------------------
    int wv   = tid >> 6;          // 0..7
    int lane = tid & 63;
    int oct  = lane & 15;         // 8-px x-run
    int row  = (lane >> 4) & 1;   // row within 2-row slab
    int half = lane >> 5;         // gaussian parity within wave's chunk
    int y_i  = slab * 2 + row;

    float x0  = ((float)(oct * 8) + 0.5f) * GV_DX - 1.0f;
    float y   = ((float)y_i + 0.5f) * GV_DX - 1.0f;
    float xx0 = x0 * x0, x0y = x0 * y, yy = y * y;
    float cA  = GV_DX * (2.0f * x0 + GV_DX);

    int chunk = (Ng + 7) >> 3;
    int g0    = wv * chunk;
    int cnt_w = Ng - g0;
    if (cnt_w > chunk) cnt_w = chunk;
    if (cnt_w < 0) cnt_w = 0;

    float aR[8], aG[8], aB[8];
    #pragma unroll
    for (int j = 0; j < 8; ++j) { aR[j] = 0.f; aG[j] = 0.f; aB[j] = 0.f; }

    #pragma unroll 2
    for (int i = half; i < cnt_w; i += 2) {
        const float4* qr = (const float4*)&sbuf[(g0 + i) * 12];
        float4 v0 = qr[0];  // A B C Dx
        float4 v1 = qr[1];  // Dy E s fr
        float4 v2 = qr[2];  // fg fb DxD CD
        float u = fmaf(v0.x, xx0,
                  fmaf(v0.y, yy,
                  fmaf(v0.z, x0y,
                  fmaf(v0.w, x0,
                  fmaf(v1.x, y, v1.y)))));
        float e = exp2f(u);
        float r = exp2f(fmaf(v0.x, cA, fmaf(v2.w, y, v2.z)));
        float s = v1.z;
        #pragma unroll
        for (int j = 0; j < 8; ++j) {
            aR[j] = fmaf(e, v1.w, aR[j]);
            aG[j] = fmaf(e, v2.x, aG[j]);
            aB[j] = fmaf(e, v2.y, aB[j]);
            if (j < 7) { e *= r; r *= s; }
        }
    }

    // ---------------- Phase 3: block reduce ---------------------------------
    #pragma unroll
    for (int j = 0; j < 8; ++j) {
        aR[j] += __shfl_xor(aR[j], 32, 64);
        aG[j] += __shfl_xor(aG[j], 32, 64);
        aB[j] += __shfl_xor(aB[j], 32, 64);
    }

    __syncthreads();  // record reads done; reuse sbuf for partial dump

    if (half == 0) {
        // slot stride 25 (coprime 32) -> conflict-free dump
        float* dst = &sbuf[(wv * 32 + lane) * 25];
        #pragma unroll
        for (int j = 0; j < 8; ++j) {
            dst[j * 3 + 0] = aR[j];
            dst[j * 3 + 1] = aG[j];
            dst[j * 3 + 2] = aB[j];
        }
    }
    __syncthreads();

    // 768 partials, 512 threads -> o-loop; write to d_ws plane
    #pragma unroll
    for (int uu = 0; uu < 2; ++uu) {
        int o = tid + uu * 512;
        if (o < 768) {
            int c  = o % 3;
            int xr = o / 3;
            int x  = xr & 127;
            int rw = xr >> 7;
            int oc = x >> 3;
            int j  = x & 7;
            int ofs = (rw * 16 + oc) * 25 + j * 3 + c;
            float sacc = 0.f;
            #pragma unroll
            for (int wvI = 0; wvI < 8; ++wvI) sacc += sbuf[wvI * 800 + ofs];
            pws[(size_t)(tile * 4 + gq) * 768 + o] = sacc;
        }
    }

    // ---------------- Phase 4: last-arriver combines -------------------------
    __threadfence();    // release: make this block's pws stores device-visible
    __syncthreads();
    if (tid == 0) {
        unsigned int old = atomicAdd(&cnt[tile], 1u);
        s_last = ((old & 3u) == 3u) ? 1 : 0;
    }
    __syncthreads();

    if (s_last) {
        __threadfence();  // acquire: invalidate caches before reading partials
        const volatile float* pv = (const volatile float*)pws;
        #pragma unroll
        for (int uu = 0; uu < 2; ++uu) {
            int o = tid + uu * 512;
            if (o < 768) {
                float sfin = 0.f;
                #pragma unroll
                for (int g = 0; g < 4; ++g)   // fixed order: deterministic
                    sfin += pv[(size_t)(tile * 4 + g) * 768 + o];
                out[(size_t)tile * 768 + o] = fminf(fmaxf(sfin, 0.0f), 1.0f);
            }
        }
    }
}

extern "C" void kernel_launch(void* const* d_in, const int* in_sizes, int n_in,
                              void* d_out, int out_size, void* d_ws, size_t ws_size,
                              hipStream_t stream) {
    const float* xyz   = (const float*)d_in[0];
    const float* chol  = (const float*)d_in[1];
    const float* feats = (const float*)d_in[2];
    const float* opac  = (const float*)d_in[3];
    float* out = (float*)d_out;
    int N = in_sizes[0] / 3;
    if (N > GV_NMAX) N = GV_NMAX;  // LDS record capacity (reference N=1024)

    // d_ws layout: partials [256 tiles * 4 quarters * 768 floats] (3 MB),
    //              then 256 uint tile counters (any init value works).
    float* pws = (float*)d_ws;
    unsigned int* cnt = (unsigned int*)((char*)d_ws
                        + (size_t)GV_T * 64 * 4 * 768 * sizeof(float));

    int blocks = GV_T * 64 * 4;  // 1024
    gv_fused_kernel<<<blocks, 512, 0, stream>>>(xyz, chol, feats, opac,
                                                out, pws, cnt, N);
}